// Round 14
// baseline (582.827 us; speedup 1.0000x reference)
//
#include <hip/hip_runtime.h>

#define OBS_STRIDE 490

typedef _Float16 half8 __attribute__((ext_vector_type(8)));
typedef _Float16 half4 __attribute__((ext_vector_type(4)));
typedef float f32x4 __attribute__((ext_vector_type(4)));

union H8 { half8 h; uint4 u; };

// Fragment table layout (uint4 per lane, 64 lanes per fragment):
//   conv1 [0,18)   conv2 [18,54)   conv3 [54,126)
//   fc   [126,638): 32 ksteps x 16 mt      (K=1024)
//   t1   [638,798): 10 ksteps x 16 mt      (K=320)
//   t2   [798,926):  8 ksteps x 16 mt      (K=256)
//   head [926,942):  8 ksteps x 2 mt       (K=256; mt0=actor, mt1 row0=critic)
#define FC_BASE 126
#define T1_BASE 638
#define T2_BASE 798
#define HD_BASE 926
#define NFRAG   942

__global__ __launch_bounds__(256) void prep_weights(
    const float* __restrict__ w1, const float* __restrict__ w2,
    const float* __restrict__ w3,
    const float* __restrict__ fcw, const float* __restrict__ t1w,
    const float* __restrict__ t2w,
    const float* __restrict__ aw,  const float* __restrict__ cw,
    uint4* __restrict__ wfrag)
{
    int gid = blockIdx.x * 256 + threadIdx.x;
    if (gid >= NFRAG * 64) return;
    int fid = gid >> 6, lane = gid & 63;
    H8 v;
    if (fid < 126) {
        const float* W; int C, sh, kt, mt;
        if (fid < 18)      { int f = fid;      W = w1; C = 9;  sh = f >> 1; kt = 0;            mt = f & 1; }
        else if (fid < 54) { int f = fid - 18; W = w2; C = 32; sh = f >> 2; kt = 0;            mt = f & 3; }
        else               { int f = fid - 54; W = w3; C = 64; sh = f >> 3; kt = (f >> 2) & 1; mt = f & 3; }
        int o  = mt * 16 + (lane & 15);
        int c0 = kt * 32 + ((lane >> 4) << 3);
        #pragma unroll
        for (int i = 0; i < 8; ++i) {
            int c = c0 + i;
            v.h[i] = (c < C) ? (_Float16)W[(o * C + c) * 9 + sh] : (_Float16)0.f;
        }
    } else {
        int o16 = lane & 15, k0 = (lane >> 4) << 3;
        if (fid < HD_BASE) {
            const float* W; int K, f;
            if (fid < T1_BASE)      { f = fid - FC_BASE; W = fcw; K = 1024; }
            else if (fid < T2_BASE) { f = fid - T1_BASE; W = t1w; K = 320;  }
            else                    { f = fid - T2_BASE; W = t2w; K = 256;  }
            int ks = f >> 4, mtg = f & 15;
            int o = mtg * 16 + o16;
            int kb = ks * 32 + k0;
            #pragma unroll
            for (int i = 0; i < 8; ++i)
                v.h[i] = (_Float16)W[(size_t)o * K + kb + i];
        } else {
            int f = fid - HD_BASE;
            int ks = f >> 1, mtg = f & 1;
            int kb = ks * 32 + k0;
            #pragma unroll
            for (int i = 0; i < 8; ++i) {
                float x;
                if (mtg == 0)      x = aw[o16 * 256 + kb + i];
                else if (o16 == 0) x = cw[kb + i];
                else               x = 0.f;
                v.h[i] = (_Float16)x;
            }
        }
    }
    wfrag[gid] = v.u;
}

// ---------------------------------------------------------------------------
// conv_kernel v6 = r13 (6-row register reuse, dx-major) + r6 (no-y-halo
// 16x18x128 = 36864B LDS, direct f16 scatter, fused zero+terrain, 4 blk/CU).
// bf[j] caches LDS row ys = wv*4 + j - 1 (j=0..5); MFMA for (row,dyi) uses
// bf[row+dyi]; out-of-range ys is wave-uniform -> skip read AND MFMAs.
// ---------------------------------------------------------------------------
template<int KT, int MT, int FRAG_BASE>
__device__ __forceinline__ void conv_layer(
    unsigned char* Abuf, const uint4* __restrict__ wfrag,
    const float* __restrict__ bias, int lane, int wv)
{
    const int x = lane & 15;
    const int q = lane >> 4;
    f32x4 acc[4][MT];
    #pragma unroll
    for (int mt = 0; mt < MT; ++mt) {
        f32x4 bv = *(const f32x4*)(bias + mt * 16 + q * 4);
        #pragma unroll
        for (int row = 0; row < 4; ++row) acc[row][mt] = bv;
    }
    #pragma unroll
    for (int dxi = 0; dxi < 3; ++dxi) {
        const int xs = x + dxi;                        // 0..17 (x-halo resident)
        #pragma unroll
        for (int kt = 0; kt < KT; ++kt) {
            const int chunk = ((kt * 4 + q) ^ (xs & 7)) << 4;
            // 6 candidate rows ys = wv*4 + j - 1 cover all (row,dyi)
            H8 bf[6];
            #pragma unroll
            for (int j = 0; j < 6; ++j) {
                const int ys = wv * 4 + j - 1;
                if (ys >= 0 && ys <= 15)               // wave-uniform
                    bf[j].h = *(const half8*)(Abuf + ys * 2304 + xs * 128 + chunk);
            }
            #pragma unroll
            for (int dyi = 0; dyi < 3; ++dyi) {
                const int sh = dyi * 3 + dxi;
                H8 wf[MT];
                #pragma unroll
                for (int mt = 0; mt < MT; ++mt)
                    wf[mt].u = wfrag[(FRAG_BASE + (sh * KT + kt) * MT + mt) * 64 + lane];
                #pragma unroll
                for (int row = 0; row < 4; ++row) {
                    const int j = row + dyi;           // bf index
                    const int ys = wv * 4 + j - 1;
                    if (ys >= 0 && ys <= 15) {         // wave-uniform skip
                        #pragma unroll
                        for (int mt = 0; mt < MT; ++mt)
                            acc[row][mt] = __builtin_amdgcn_mfma_f32_16x16x32_f16(
                                wf[mt].h, bf[j].h, acc[row][mt], 0, 0, 0);
                    }
                }
            }
        }
    }
    __syncthreads();
    const int xs1 = x + 1;
    #pragma unroll
    for (int row = 0; row < 4; ++row) {
        const int yi = wv * 4 + row;                   // stored row 0..15
        #pragma unroll
        for (int mt = 0; mt < MT; ++mt) {
            half4 hv;
            #pragma unroll
            for (int r = 0; r < 4; ++r) hv[r] = (_Float16)fmaxf(acc[row][mt][r], 0.f);
            const int ob = mt * 32 + q * 8;
            const int addr = yi * 2304 + xs1 * 128 + ((((ob >> 4) ^ (xs1 & 7))) << 4) + (ob & 15);
            *(half4*)(Abuf + addr) = hv;
        }
    }
    __syncthreads();
}

__global__ __launch_bounds__(256, 4) void conv_kernel(
    const float* __restrict__ obs,
    const uint4* __restrict__ wfrag,
    const float* __restrict__ b1, const float* __restrict__ b2,
    const float* __restrict__ b3,
    _Float16* __restrict__ pooled)
{
    __shared__ alignas(16) unsigned char Abuf[16 * 18 * 128];   // 36864 B

    const int tid = threadIdx.x;
    const int b = blockIdx.x;
    const float* ob = obs + (size_t)b * OBS_STRIDE;

    // fused zero + terrain fill (2304 uint4 = 9 iters x 256)
    {
        uint4* A4 = (uint4*)Abuf;
        #pragma unroll
        for (int it = 0; it < 9; ++it) {
            int i = tid + it * 256;
            int r0 = i / 144;                        // row 0..15
            int rem = i - r0 * 144;
            int xs = rem >> 3, pc = rem & 7;
            int c = pc ^ (xs & 7);
            uint4 v = {0, 0, 0, 0};
            if (c == 0 && xs >= 1 && xs <= 16) {
                H8 h;
                #pragma unroll
                for (int j = 0; j < 8; ++j) h.h[j] = (_Float16)0.f;
                h.h[0] = (_Float16)ob[r0 * 16 + xs - 1];
                v = h.u;
            }
            A4[i] = v;
        }
    }
    __syncthreads();

    // unit scatter: argsort cells DISTINCT -> direct f16 writes, no atomics
    if (tid < 20) {
        const float* up = ob + 256 + tid * 10;
        float team = up[1], rf = up[2], cf = up[3];
        float hp = up[4], mv = up[5], ac = up[6];
        if (hp > 0.f) {
            int r = (int)(rf * 15.f), c = (int)(cf * 15.f);  // trunc == astype(int32)
            const unsigned base = (unsigned)(r * 2304 + (c + 1) * 128);
            const int sw = (c + 1) & 7;
#define SCAT_W(CH, VAL) { const int obyte = (CH) * 2;                                   \
        *(_Float16*)(Abuf + base + ((((obyte >> 4) ^ sw)) << 4) + (obyte & 15)) =       \
            (_Float16)(VAL); }
            if (team < 0.5f) {            // blue: ones,hp,moved,acted -> ch1,3,5,6
                SCAT_W(1, 1.f) SCAT_W(3, hp) SCAT_W(5, mv) SCAT_W(6, ac)
            } else {                      // red:  ones,hp,moved,acted -> ch2,4,7,8
                SCAT_W(2, 1.f) SCAT_W(4, hp) SCAT_W(7, mv) SCAT_W(8, ac)
            }
#undef SCAT_W
        }
    }
    __syncthreads();

    const int lane = tid & 63, wv = tid >> 6;
    conv_layer<1, 2, 0 >(Abuf, wfrag, b1, lane, wv);   // 9(pad->32) -> 32
    conv_layer<1, 4, 18>(Abuf, wfrag, b2, lane, wv);   // 32 -> 64
    conv_layer<2, 4, 54>(Abuf, wfrag, b3, lane, wv);   // 64 -> 64

    // 4x4 avg pool -> pooled[b][ch*16 + ph*4 + pw] (f16)
    {
        int qq = tid & 15, cg = tid >> 4;
        int ph = qq >> 2, pw = qq & 3;
        int ch0 = cg * 4;
        float s[4] = {0.f, 0.f, 0.f, 0.f};
        int ob2 = ch0 * 2;
        #pragma unroll
        for (int dy = 0; dy < 4; ++dy) {
            int yi = ph * 4 + dy;                      // stored row
            #pragma unroll
            for (int dx = 0; dx < 4; ++dx) {
                int xs = pw * 4 + dx + 1;
                int addr = yi * 2304 + xs * 128 + ((((ob2 >> 4) ^ (xs & 7))) << 4) + (ob2 & 15);
                half4 hv = *(const half4*)(Abuf + addr);
                #pragma unroll
                for (int cc = 0; cc < 4; ++cc) s[cc] += (float)hv[cc];
            }
        }
        _Float16* pb = pooled + (size_t)b * 1024;
        #pragma unroll
        for (int cc = 0; cc < 4; ++cc)
            pb[(ch0 + cc) * 16 + qq] = (_Float16)(s[cc] * 0.0625f);
    }
}

// ---------------------------------------------------------------------------
// tail_kernel (MFMA): UNCHANGED (passed, ~30-50us).
// ---------------------------------------------------------------------------
__global__ __launch_bounds__(256) void tail_kernel(
    const float* __restrict__ obs,
    const _Float16* __restrict__ pooled,
    const uint4* __restrict__ wfrag,
    const float* __restrict__ fcb,
    const float* __restrict__ u1w, const float* __restrict__ u1b,
    const float* __restrict__ u2w, const float* __restrict__ u2b,
    const float* __restrict__ t1b, const float* __restrict__ t2b,
    const float* __restrict__ ab,  const float* __restrict__ cb,
    float* __restrict__ out, int NB)
{
    __shared__ alignas(16) _Float16 tcT[32][344];   // 22016 B
    __shared__ alignas(16) _Float16 uh[32][72];     //  4608 B

    const int tid  = threadIdx.x;
    const int lane = tid & 63, w = tid >> 6;
    const int nl   = lane & 15, q = lane >> 4;
    const int r0   = blockIdx.x * 32;

    // ---- unit MLP u1 (scalar): 32 rows x 8 threads each ----
    {
        const int r = tid >> 3, t8 = tid & 7;
        const float* up = obs + (size_t)(r0 + r) * OBS_STRIDE + 458;
        float xin[32];
        #pragma unroll
        for (int k2 = 0; k2 < 16; ++k2) {
            float2 v = *(const float2*)(up + k2 * 2);
            xin[k2 * 2] = v.x; xin[k2 * 2 + 1] = v.y;
        }
        #pragma unroll
        for (int oo = 0; oo < 8; ++oo) {
            int o = t8 * 8 + oo;
            float a = u1b[o];
            const float* wr = u1w + o * 32;
            #pragma unroll
            for (int k = 0; k < 32; ++k) a = fmaf(xin[k], wr[k], a);
            uh[r][o] = (_Float16)fmaxf(a, 0.f);
        }
    }
    __syncthreads();

    // ---- u2 -> tcT[:, 256..319] ----
    {
        const int r = tid >> 3, t8 = tid & 7;
        float xin[64];
        #pragma unroll
        for (int k8 = 0; k8 < 8; ++k8) {
            half8 v = *(const half8*)&uh[r][k8 * 8];
            #pragma unroll
            for (int j = 0; j < 8; ++j) xin[k8 * 8 + j] = (float)v[j];
        }
        #pragma unroll
        for (int oo = 0; oo < 8; ++oo) {
            int o = t8 * 8 + oo;
            float a = u2b[o];
            const float* wr = u2w + o * 64;
            #pragma unroll
            for (int k = 0; k < 64; ++k) a = fmaf(xin[k], wr[k], a);
            tcT[r][256 + o] = (_Float16)fmaxf(a, 0.f);
        }
    }

    // ---- fc: K=1024, 32 ksteps, B-frags direct from global pooled ----
    {
        f32x4 acc[4][2];
        #pragma unroll
        for (int mt = 0; mt < 4; ++mt) {
            f32x4 bv = *(const f32x4*)(fcb + (w * 4 + mt) * 16 + q * 4);
            acc[mt][0] = bv; acc[mt][1] = bv;
        }
        for (int ks = 0; ks < 32; ++ks) {
            H8 bf[2];
            #pragma unroll
            for (int g = 0; g < 2; ++g)
                bf[g].u = *(const uint4*)(pooled + (size_t)(r0 + g * 16 + nl) * 1024 + ks * 32 + q * 8);
            #pragma unroll
            for (int mt = 0; mt < 4; ++mt) {
                H8 af; af.u = wfrag[(size_t)(FC_BASE + ks * 16 + w * 4 + mt) * 64 + lane];
                #pragma unroll
                for (int g = 0; g < 2; ++g)
                    acc[mt][g] = __builtin_amdgcn_mfma_f32_16x16x32_f16(af.h, bf[g].h, acc[mt][g], 0, 0, 0);
            }
        }
        #pragma unroll
        for (int mt = 0; mt < 4; ++mt)
            #pragma unroll
            for (int g = 0; g < 2; ++g) {
                half4 hv;
                #pragma unroll
                for (int r = 0; r < 4; ++r) hv[r] = (_Float16)fmaxf(acc[mt][g][r], 0.f);
                *(half4*)&tcT[g * 16 + nl][(w * 4 + mt) * 16 + q * 4] = hv;
            }
    }
    __syncthreads();

    // ---- t1: K=320, 10 ksteps, B from tcT; in-place overwrite ----
    {
        f32x4 acc[4][2];
        #pragma unroll
        for (int mt = 0; mt < 4; ++mt) {
            f32x4 bv = *(const f32x4*)(t1b + (w * 4 + mt) * 16 + q * 4);
            acc[mt][0] = bv; acc[mt][1] = bv;
        }
        for (int ks = 0; ks < 10; ++ks) {
            H8 bf[2];
            #pragma unroll
            for (int g = 0; g < 2; ++g)
                bf[g].h = *(const half8*)&tcT[g * 16 + nl][ks * 32 + q * 8];
            #pragma unroll
            for (int mt = 0; mt < 4; ++mt) {
                H8 af; af.u = wfrag[(size_t)(T1_BASE + ks * 16 + w * 4 + mt) * 64 + lane];
                #pragma unroll
                for (int g = 0; g < 2; ++g)
                    acc[mt][g] = __builtin_amdgcn_mfma_f32_16x16x32_f16(af.h, bf[g].h, acc[mt][g], 0, 0, 0);
            }
        }
        __syncthreads();
        #pragma unroll
        for (int mt = 0; mt < 4; ++mt)
            #pragma unroll
            for (int g = 0; g < 2; ++g) {
                half4 hv;
                #pragma unroll
                for (int r = 0; r < 4; ++r) hv[r] = (_Float16)fmaxf(acc[mt][g][r], 0.f);
                *(half4*)&tcT[g * 16 + nl][(w * 4 + mt) * 16 + q * 4] = hv;
            }
    }
    __syncthreads();

    // ---- t2: K=256, 8 ksteps ----
    {
        f32x4 acc[4][2];
        #pragma unroll
        for (int mt = 0; mt < 4; ++mt) {
            f32x4 bv = *(const f32x4*)(t2b + (w * 4 + mt) * 16 + q * 4);
            acc[mt][0] = bv; acc[mt][1] = bv;
        }
        for (int ks = 0; ks < 8; ++ks) {
            H8 bf[2];
            #pragma unroll
            for (int g = 0; g < 2; ++g)
                bf[g].h = *(const half8*)&tcT[g * 16 + nl][ks * 32 + q * 8];
            #pragma unroll
            for (int mt = 0; mt < 4; ++mt) {
                H8 af; af.u = wfrag[(size_t)(T2_BASE + ks * 16 + w * 4 + mt) * 64 + lane];
                #pragma unroll
                for (int g = 0; g < 2; ++g)
                    acc[mt][g] = __builtin_amdgcn_mfma_f32_16x16x32_f16(af.h, bf[g].h, acc[mt][g], 0, 0, 0);
            }
        }
        __syncthreads();
        #pragma unroll
        for (int mt = 0; mt < 4; ++mt)
            #pragma unroll
            for (int g = 0; g < 2; ++g) {
                half4 hv;
                #pragma unroll
                for (int r = 0; r < 4; ++r) hv[r] = (_Float16)fmaxf(acc[mt][g][r], 0.f);
                *(half4*)&tcT[g * 16 + nl][(w * 4 + mt) * 16 + q * 4] = hv;
            }
    }
    __syncthreads();

    // ---- heads: K=256, 8 ksteps; wave0 = actor, wave1 = critic ----
    if (w < 2) {
        f32x4 acc[2];
        if (w == 0) {
            f32x4 bv = *(const f32x4*)(ab + q * 4);
            acc[0] = bv; acc[1] = bv;
        } else {
            f32x4 bv = {0.f, 0.f, 0.f, 0.f};
            if (q == 0) bv[0] = cb[0];
            acc[0] = bv; acc[1] = bv;
        }
        for (int ks = 0; ks < 8; ++ks) {
            H8 af; af.u = wfrag[(size_t)(HD_BASE + ks * 2 + w) * 64 + lane];
            #pragma unroll
            for (int g = 0; g < 2; ++g) {
                half8 bf = *(const half8*)&tcT[g * 16 + nl][ks * 32 + q * 8];
                acc[g] = __builtin_amdgcn_mfma_f32_16x16x32_f16(af.h, bf, acc[g], 0, 0, 0);
            }
        }
        if (w == 0) {
            #pragma unroll
            for (int g = 0; g < 2; ++g) {
                float4 o4 = {acc[g][0], acc[g][1], acc[g][2], acc[g][3]};
                *(float4*)(out + (size_t)(r0 + g * 16 + nl) * 16 + q * 4) = o4;
            }
        } else if (q == 0) {
            #pragma unroll
            for (int g = 0; g < 2; ++g)
                out[(size_t)NB * 16 + r0 + g * 16 + nl] = acc[g][0];
        }
    }
}

extern "C" void kernel_launch(void* const* d_in, const int* in_sizes, int n_in,
                              void* d_out, int out_size, void* d_ws, size_t ws_size,
                              hipStream_t stream)
{
    const float* obs = (const float*)d_in[0];
    const float* w1  = (const float*)d_in[1];
    const float* b1  = (const float*)d_in[2];
    const float* w2  = (const float*)d_in[3];
    const float* b2  = (const float*)d_in[4];
    const float* w3  = (const float*)d_in[5];
    const float* b3  = (const float*)d_in[6];
    const float* fcw = (const float*)d_in[7];
    const float* fcb = (const float*)d_in[8];
    const float* u1w = (const float*)d_in[9];
    const float* u1b = (const float*)d_in[10];
    const float* u2w = (const float*)d_in[11];
    const float* u2b = (const float*)d_in[12];
    const float* t1w = (const float*)d_in[13];
    const float* t1b = (const float*)d_in[14];
    const float* t2w = (const float*)d_in[15];
    const float* t2b = (const float*)d_in[16];
    const float* aw  = (const float*)d_in[17];
    const float* ab  = (const float*)d_in[18];
    const float* cw  = (const float*)d_in[19];
    const float* cb  = (const float*)d_in[20];

    const int NB = in_sizes[0] / OBS_STRIDE;                       // 16384
    _Float16* pooled = (_Float16*)d_ws;                            // 32 MB
    uint4* wfrag = (uint4*)((char*)d_ws + (size_t)NB * 1024 * 2);  // 942 KB

    prep_weights<<<(NFRAG * 64 + 255) / 256, 256, 0, stream>>>(
        w1, w2, w3, fcw, t1w, t2w, aw, cw, wfrag);
    conv_kernel<<<NB, 256, 0, stream>>>(obs, (const uint4*)wfrag, b1, b2, b3, pooled);
    tail_kernel<<<NB / 32, 256, 0, stream>>>(obs, pooled, (const uint4*)wfrag,
                                             fcb, u1w, u1b, u2w, u2b,
                                             t1b, t2b, ab, cb,
                                             (float*)d_out, NB);
}

// Round 15
// 570.318 us; speedup vs baseline: 1.0219x; 1.0219x over previous
//
#include <hip/hip_runtime.h>

#define OBS_STRIDE 490

typedef _Float16 half8 __attribute__((ext_vector_type(8)));
typedef _Float16 half4 __attribute__((ext_vector_type(4)));
typedef float f32x4 __attribute__((ext_vector_type(4)));

union H8 { half8 h; uint4 u; };

// Fragment table layout (uint4 per lane, 64 lanes per fragment):
//   conv1 [0,18)   conv2 [18,54)   conv3 [54,126)
//   fc   [126,638): 32 ksteps x 16 mt      (K=1024)
//   t1   [638,798): 10 ksteps x 16 mt      (K=320)
//   t2   [798,926):  8 ksteps x 16 mt      (K=256)
//   head [926,942):  8 ksteps x 2 mt       (K=256; mt0=actor, mt1 row0=critic)
#define FC_BASE 126
#define T1_BASE 638
#define T2_BASE 798
#define HD_BASE 926
#define NFRAG   942

__global__ __launch_bounds__(256) void prep_weights(
    const float* __restrict__ w1, const float* __restrict__ w2,
    const float* __restrict__ w3,
    const float* __restrict__ fcw, const float* __restrict__ t1w,
    const float* __restrict__ t2w,
    const float* __restrict__ aw,  const float* __restrict__ cw,
    uint4* __restrict__ wfrag)
{
    int gid = blockIdx.x * 256 + threadIdx.x;
    if (gid >= NFRAG * 64) return;
    int fid = gid >> 6, lane = gid & 63;
    H8 v;
    if (fid < 126) {
        const float* W; int C, sh, kt, mt;
        if (fid < 18)      { int f = fid;      W = w1; C = 9;  sh = f >> 1; kt = 0;            mt = f & 1; }
        else if (fid < 54) { int f = fid - 18; W = w2; C = 32; sh = f >> 2; kt = 0;            mt = f & 3; }
        else               { int f = fid - 54; W = w3; C = 64; sh = f >> 3; kt = (f >> 2) & 1; mt = f & 3; }
        int o  = mt * 16 + (lane & 15);
        int c0 = kt * 32 + ((lane >> 4) << 3);
        #pragma unroll
        for (int i = 0; i < 8; ++i) {
            int c = c0 + i;
            v.h[i] = (c < C) ? (_Float16)W[(o * C + c) * 9 + sh] : (_Float16)0.f;
        }
    } else {
        int o16 = lane & 15, k0 = (lane >> 4) << 3;
        if (fid < HD_BASE) {
            const float* W; int K, f;
            if (fid < T1_BASE)      { f = fid - FC_BASE; W = fcw; K = 1024; }
            else if (fid < T2_BASE) { f = fid - T1_BASE; W = t1w; K = 320;  }
            else                    { f = fid - T2_BASE; W = t2w; K = 256;  }
            int ks = f >> 4, mtg = f & 15;
            int o = mtg * 16 + o16;
            int kb = ks * 32 + k0;
            #pragma unroll
            for (int i = 0; i < 8; ++i)
                v.h[i] = (_Float16)W[(size_t)o * K + kb + i];
        } else {
            int f = fid - HD_BASE;
            int ks = f >> 1, mtg = f & 1;
            int kb = ks * 32 + k0;
            #pragma unroll
            for (int i = 0; i < 8; ++i) {
                float x;
                if (mtg == 0)      x = aw[o16 * 256 + kb + i];
                else if (o16 == 0) x = cw[kb + i];
                else               x = 0.f;
                v.h[i] = (_Float16)x;
            }
        }
    }
    wfrag[gid] = v.u;
}

// ---------------------------------------------------------------------------
// conv_kernel v6b = r14 structure (no-y-halo 16x18x128 = 36864B LDS, direct
// f16 scatter, fused zero+terrain, 6-row bf register reuse) with the VGPR
// cap RELEASED: launch_bounds(256,2). r14's (256,4) forced 64 VGPR -> scratch
// spills (WRITE_SIZE 33MB -> 330MB). Occupancy now comes from LDS: 4 blk/CU.
// ---------------------------------------------------------------------------
template<int KT, int MT, int FRAG_BASE>
__device__ __forceinline__ void conv_layer(
    unsigned char* Abuf, const uint4* __restrict__ wfrag,
    const float* __restrict__ bias, int lane, int wv)
{
    const int x = lane & 15;
    const int q = lane >> 4;
    f32x4 acc[4][MT];
    #pragma unroll
    for (int mt = 0; mt < MT; ++mt) {
        f32x4 bv = *(const f32x4*)(bias + mt * 16 + q * 4);
        #pragma unroll
        for (int row = 0; row < 4; ++row) acc[row][mt] = bv;
    }
    #pragma unroll
    for (int dxi = 0; dxi < 3; ++dxi) {
        const int xs = x + dxi;                        // 0..17 (x-halo resident)
        #pragma unroll
        for (int kt = 0; kt < KT; ++kt) {
            const int chunk = ((kt * 4 + q) ^ (xs & 7)) << 4;
            // 6 candidate rows ys = wv*4 + j - 1 cover all (row,dyi)
            H8 bf[6];
            #pragma unroll
            for (int j = 0; j < 6; ++j) {
                const int ys = wv * 4 + j - 1;
                if (ys >= 0 && ys <= 15)               // wave-uniform
                    bf[j].h = *(const half8*)(Abuf + ys * 2304 + xs * 128 + chunk);
            }
            #pragma unroll
            for (int dyi = 0; dyi < 3; ++dyi) {
                const int sh = dyi * 3 + dxi;
                H8 wf[MT];
                #pragma unroll
                for (int mt = 0; mt < MT; ++mt)
                    wf[mt].u = wfrag[(FRAG_BASE + (sh * KT + kt) * MT + mt) * 64 + lane];
                #pragma unroll
                for (int row = 0; row < 4; ++row) {
                    const int j = row + dyi;           // bf index
                    const int ys = wv * 4 + j - 1;
                    if (ys >= 0 && ys <= 15) {         // wave-uniform skip
                        #pragma unroll
                        for (int mt = 0; mt < MT; ++mt)
                            acc[row][mt] = __builtin_amdgcn_mfma_f32_16x16x32_f16(
                                wf[mt].h, bf[j].h, acc[row][mt], 0, 0, 0);
                    }
                }
            }
        }
    }
    __syncthreads();
    const int xs1 = x + 1;
    #pragma unroll
    for (int row = 0; row < 4; ++row) {
        const int yi = wv * 4 + row;                   // stored row 0..15
        #pragma unroll
        for (int mt = 0; mt < MT; ++mt) {
            half4 hv;
            #pragma unroll
            for (int r = 0; r < 4; ++r) hv[r] = (_Float16)fmaxf(acc[row][mt][r], 0.f);
            const int ob = mt * 32 + q * 8;
            const int addr = yi * 2304 + xs1 * 128 + ((((ob >> 4) ^ (xs1 & 7))) << 4) + (ob & 15);
            *(half4*)(Abuf + addr) = hv;
        }
    }
    __syncthreads();
}

__global__ __launch_bounds__(256, 2) void conv_kernel(
    const float* __restrict__ obs,
    const uint4* __restrict__ wfrag,
    const float* __restrict__ b1, const float* __restrict__ b2,
    const float* __restrict__ b3,
    _Float16* __restrict__ pooled)
{
    __shared__ alignas(16) unsigned char Abuf[16 * 18 * 128];   // 36864 B

    const int tid = threadIdx.x;
    const int b = blockIdx.x;
    const float* ob = obs + (size_t)b * OBS_STRIDE;

    // fused zero + terrain fill (2304 uint4 = 9 iters x 256)
    {
        uint4* A4 = (uint4*)Abuf;
        #pragma unroll
        for (int it = 0; it < 9; ++it) {
            int i = tid + it * 256;
            int r0 = i / 144;                        // row 0..15
            int rem = i - r0 * 144;
            int xs = rem >> 3, pc = rem & 7;
            int c = pc ^ (xs & 7);
            uint4 v = {0, 0, 0, 0};
            if (c == 0 && xs >= 1 && xs <= 16) {
                H8 h;
                #pragma unroll
                for (int j = 0; j < 8; ++j) h.h[j] = (_Float16)0.f;
                h.h[0] = (_Float16)ob[r0 * 16 + xs - 1];
                v = h.u;
            }
            A4[i] = v;
        }
    }
    __syncthreads();

    // unit scatter: argsort cells DISTINCT -> direct f16 writes, no atomics
    if (tid < 20) {
        const float* up = ob + 256 + tid * 10;
        float team = up[1], rf = up[2], cf = up[3];
        float hp = up[4], mv = up[5], ac = up[6];
        if (hp > 0.f) {
            int r = (int)(rf * 15.f), c = (int)(cf * 15.f);  // trunc == astype(int32)
            const unsigned base = (unsigned)(r * 2304 + (c + 1) * 128);
            const int sw = (c + 1) & 7;
#define SCAT_W(CH, VAL) { const int obyte = (CH) * 2;                                   \
        *(_Float16*)(Abuf + base + ((((obyte >> 4) ^ sw)) << 4) + (obyte & 15)) =       \
            (_Float16)(VAL); }
            if (team < 0.5f) {            // blue: ones,hp,moved,acted -> ch1,3,5,6
                SCAT_W(1, 1.f) SCAT_W(3, hp) SCAT_W(5, mv) SCAT_W(6, ac)
            } else {                      // red:  ones,hp,moved,acted -> ch2,4,7,8
                SCAT_W(2, 1.f) SCAT_W(4, hp) SCAT_W(7, mv) SCAT_W(8, ac)
            }
#undef SCAT_W
        }
    }
    __syncthreads();

    const int lane = tid & 63, wv = tid >> 6;
    conv_layer<1, 2, 0 >(Abuf, wfrag, b1, lane, wv);   // 9(pad->32) -> 32
    conv_layer<1, 4, 18>(Abuf, wfrag, b2, lane, wv);   // 32 -> 64
    conv_layer<2, 4, 54>(Abuf, wfrag, b3, lane, wv);   // 64 -> 64

    // 4x4 avg pool -> pooled[b][ch*16 + ph*4 + pw] (f16)
    {
        int qq = tid & 15, cg = tid >> 4;
        int ph = qq >> 2, pw = qq & 3;
        int ch0 = cg * 4;
        float s[4] = {0.f, 0.f, 0.f, 0.f};
        int ob2 = ch0 * 2;
        #pragma unroll
        for (int dy = 0; dy < 4; ++dy) {
            int yi = ph * 4 + dy;                      // stored row
            #pragma unroll
            for (int dx = 0; dx < 4; ++dx) {
                int xs = pw * 4 + dx + 1;
                int addr = yi * 2304 + xs * 128 + ((((ob2 >> 4) ^ (xs & 7))) << 4) + (ob2 & 15);
                half4 hv = *(const half4*)(Abuf + addr);
                #pragma unroll
                for (int cc = 0; cc < 4; ++cc) s[cc] += (float)hv[cc];
            }
        }
        _Float16* pb = pooled + (size_t)b * 1024;
        #pragma unroll
        for (int cc = 0; cc < 4; ++cc)
            pb[(ch0 + cc) * 16 + qq] = (_Float16)(s[cc] * 0.0625f);
    }
}

// ---------------------------------------------------------------------------
// tail_kernel (MFMA): UNCHANGED (passed, ~30-50us).
// ---------------------------------------------------------------------------
__global__ __launch_bounds__(256) void tail_kernel(
    const float* __restrict__ obs,
    const _Float16* __restrict__ pooled,
    const uint4* __restrict__ wfrag,
    const float* __restrict__ fcb,
    const float* __restrict__ u1w, const float* __restrict__ u1b,
    const float* __restrict__ u2w, const float* __restrict__ u2b,
    const float* __restrict__ t1b, const float* __restrict__ t2b,
    const float* __restrict__ ab,  const float* __restrict__ cb,
    float* __restrict__ out, int NB)
{
    __shared__ alignas(16) _Float16 tcT[32][344];   // 22016 B
    __shared__ alignas(16) _Float16 uh[32][72];     //  4608 B

    const int tid  = threadIdx.x;
    const int lane = tid & 63, w = tid >> 6;
    const int nl   = lane & 15, q = lane >> 4;
    const int r0   = blockIdx.x * 32;

    // ---- unit MLP u1 (scalar): 32 rows x 8 threads each ----
    {
        const int r = tid >> 3, t8 = tid & 7;
        const float* up = obs + (size_t)(r0 + r) * OBS_STRIDE + 458;
        float xin[32];
        #pragma unroll
        for (int k2 = 0; k2 < 16; ++k2) {
            float2 v = *(const float2*)(up + k2 * 2);
            xin[k2 * 2] = v.x; xin[k2 * 2 + 1] = v.y;
        }
        #pragma unroll
        for (int oo = 0; oo < 8; ++oo) {
            int o = t8 * 8 + oo;
            float a = u1b[o];
            const float* wr = u1w + o * 32;
            #pragma unroll
            for (int k = 0; k < 32; ++k) a = fmaf(xin[k], wr[k], a);
            uh[r][o] = (_Float16)fmaxf(a, 0.f);
        }
    }
    __syncthreads();

    // ---- u2 -> tcT[:, 256..319] ----
    {
        const int r = tid >> 3, t8 = tid & 7;
        float xin[64];
        #pragma unroll
        for (int k8 = 0; k8 < 8; ++k8) {
            half8 v = *(const half8*)&uh[r][k8 * 8];
            #pragma unroll
            for (int j = 0; j < 8; ++j) xin[k8 * 8 + j] = (float)v[j];
        }
        #pragma unroll
        for (int oo = 0; oo < 8; ++oo) {
            int o = t8 * 8 + oo;
            float a = u2b[o];
            const float* wr = u2w + o * 64;
            #pragma unroll
            for (int k = 0; k < 64; ++k) a = fmaf(xin[k], wr[k], a);
            tcT[r][256 + o] = (_Float16)fmaxf(a, 0.f);
        }
    }

    // ---- fc: K=1024, 32 ksteps, B-frags direct from global pooled ----
    {
        f32x4 acc[4][2];
        #pragma unroll
        for (int mt = 0; mt < 4; ++mt) {
            f32x4 bv = *(const f32x4*)(fcb + (w * 4 + mt) * 16 + q * 4);
            acc[mt][0] = bv; acc[mt][1] = bv;
        }
        for (int ks = 0; ks < 32; ++ks) {
            H8 bf[2];
            #pragma unroll
            for (int g = 0; g < 2; ++g)
                bf[g].u = *(const uint4*)(pooled + (size_t)(r0 + g * 16 + nl) * 1024 + ks * 32 + q * 8);
            #pragma unroll
            for (int mt = 0; mt < 4; ++mt) {
                H8 af; af.u = wfrag[(size_t)(FC_BASE + ks * 16 + w * 4 + mt) * 64 + lane];
                #pragma unroll
                for (int g = 0; g < 2; ++g)
                    acc[mt][g] = __builtin_amdgcn_mfma_f32_16x16x32_f16(af.h, bf[g].h, acc[mt][g], 0, 0, 0);
            }
        }
        #pragma unroll
        for (int mt = 0; mt < 4; ++mt)
            #pragma unroll
            for (int g = 0; g < 2; ++g) {
                half4 hv;
                #pragma unroll
                for (int r = 0; r < 4; ++r) hv[r] = (_Float16)fmaxf(acc[mt][g][r], 0.f);
                *(half4*)&tcT[g * 16 + nl][(w * 4 + mt) * 16 + q * 4] = hv;
            }
    }
    __syncthreads();

    // ---- t1: K=320, 10 ksteps, B from tcT; in-place overwrite ----
    {
        f32x4 acc[4][2];
        #pragma unroll
        for (int mt = 0; mt < 4; ++mt) {
            f32x4 bv = *(const f32x4*)(t1b + (w * 4 + mt) * 16 + q * 4);
            acc[mt][0] = bv; acc[mt][1] = bv;
        }
        for (int ks = 0; ks < 10; ++ks) {
            H8 bf[2];
            #pragma unroll
            for (int g = 0; g < 2; ++g)
                bf[g].h = *(const half8*)&tcT[g * 16 + nl][ks * 32 + q * 8];
            #pragma unroll
            for (int mt = 0; mt < 4; ++mt) {
                H8 af; af.u = wfrag[(size_t)(T1_BASE + ks * 16 + w * 4 + mt) * 64 + lane];
                #pragma unroll
                for (int g = 0; g < 2; ++g)
                    acc[mt][g] = __builtin_amdgcn_mfma_f32_16x16x32_f16(af.h, bf[g].h, acc[mt][g], 0, 0, 0);
            }
        }
        __syncthreads();
        #pragma unroll
        for (int mt = 0; mt < 4; ++mt)
            #pragma unroll
            for (int g = 0; g < 2; ++g) {
                half4 hv;
                #pragma unroll
                for (int r = 0; r < 4; ++r) hv[r] = (_Float16)fmaxf(acc[mt][g][r], 0.f);
                *(half4*)&tcT[g * 16 + nl][(w * 4 + mt) * 16 + q * 4] = hv;
            }
    }
    __syncthreads();

    // ---- t2: K=256, 8 ksteps ----
    {
        f32x4 acc[4][2];
        #pragma unroll
        for (int mt = 0; mt < 4; ++mt) {
            f32x4 bv = *(const f32x4*)(t2b + (w * 4 + mt) * 16 + q * 4);
            acc[mt][0] = bv; acc[mt][1] = bv;
        }
        for (int ks = 0; ks < 8; ++ks) {
            H8 bf[2];
            #pragma unroll
            for (int g = 0; g < 2; ++g)
                bf[g].h = *(const half8*)&tcT[g * 16 + nl][ks * 32 + q * 8];
            #pragma unroll
            for (int mt = 0; mt < 4; ++mt) {
                H8 af; af.u = wfrag[(size_t)(T2_BASE + ks * 16 + w * 4 + mt) * 64 + lane];
                #pragma unroll
                for (int g = 0; g < 2; ++g)
                    acc[mt][g] = __builtin_amdgcn_mfma_f32_16x16x32_f16(af.h, bf[g].h, acc[mt][g], 0, 0, 0);
            }
        }
        __syncthreads();
        #pragma unroll
        for (int mt = 0; mt < 4; ++mt)
            #pragma unroll
            for (int g = 0; g < 2; ++g) {
                half4 hv;
                #pragma unroll
                for (int r = 0; r < 4; ++r) hv[r] = (_Float16)fmaxf(acc[mt][g][r], 0.f);
                *(half4*)&tcT[g * 16 + nl][(w * 4 + mt) * 16 + q * 4] = hv;
            }
    }
    __syncthreads();

    // ---- heads: K=256, 8 ksteps; wave0 = actor, wave1 = critic ----
    if (w < 2) {
        f32x4 acc[2];
        if (w == 0) {
            f32x4 bv = *(const f32x4*)(ab + q * 4);
            acc[0] = bv; acc[1] = bv;
        } else {
            f32x4 bv = {0.f, 0.f, 0.f, 0.f};
            if (q == 0) bv[0] = cb[0];
            acc[0] = bv; acc[1] = bv;
        }
        for (int ks = 0; ks < 8; ++ks) {
            H8 af; af.u = wfrag[(size_t)(HD_BASE + ks * 2 + w) * 64 + lane];
            #pragma unroll
            for (int g = 0; g < 2; ++g) {
                half8 bf = *(const half8*)&tcT[g * 16 + nl][ks * 32 + q * 8];
                acc[g] = __builtin_amdgcn_mfma_f32_16x16x32_f16(af.h, bf, acc[g], 0, 0, 0);
            }
        }
        if (w == 0) {
            #pragma unroll
            for (int g = 0; g < 2; ++g) {
                float4 o4 = {acc[g][0], acc[g][1], acc[g][2], acc[g][3]};
                *(float4*)(out + (size_t)(r0 + g * 16 + nl) * 16 + q * 4) = o4;
            }
        } else if (q == 0) {
            #pragma unroll
            for (int g = 0; g < 2; ++g)
                out[(size_t)NB * 16 + r0 + g * 16 + nl] = acc[g][0];
        }
    }
}

extern "C" void kernel_launch(void* const* d_in, const int* in_sizes, int n_in,
                              void* d_out, int out_size, void* d_ws, size_t ws_size,
                              hipStream_t stream)
{
    const float* obs = (const float*)d_in[0];
    const float* w1  = (const float*)d_in[1];
    const float* b1  = (const float*)d_in[2];
    const float* w2  = (const float*)d_in[3];
    const float* b2  = (const float*)d_in[4];
    const float* w3  = (const float*)d_in[5];
    const float* b3  = (const float*)d_in[6];
    const float* fcw = (const float*)d_in[7];
    const float* fcb = (const float*)d_in[8];
    const float* u1w = (const float*)d_in[9];
    const float* u1b = (const float*)d_in[10];
    const float* u2w = (const float*)d_in[11];
    const float* u2b = (const float*)d_in[12];
    const float* t1w = (const float*)d_in[13];
    const float* t1b = (const float*)d_in[14];
    const float* t2w = (const float*)d_in[15];
    const float* t2b = (const float*)d_in[16];
    const float* aw  = (const float*)d_in[17];
    const float* ab  = (const float*)d_in[18];
    const float* cw  = (const float*)d_in[19];
    const float* cb  = (const float*)d_in[20];

    const int NB = in_sizes[0] / OBS_STRIDE;                       // 16384
    _Float16* pooled = (_Float16*)d_ws;                            // 32 MB
    uint4* wfrag = (uint4*)((char*)d_ws + (size_t)NB * 1024 * 2);  // 942 KB

    prep_weights<<<(NFRAG * 64 + 255) / 256, 256, 0, stream>>>(
        w1, w2, w3, fcw, t1w, t2w, aw, cw, wfrag);
    conv_kernel<<<NB, 256, 0, stream>>>(obs, (const uint4*)wfrag, b1, b2, b3, pooled);
    tail_kernel<<<NB / 32, 256, 0, stream>>>(obs, pooled, (const uint4*)wfrag,
                                             fcb, u1w, u1b, u2w, u2b,
                                             t1b, t2b, ab, cb,
                                             (float*)d_out, NB);
}

// Round 16
// 519.105 us; speedup vs baseline: 1.1228x; 1.0987x over previous
//
#include <hip/hip_runtime.h>

#define OBS_STRIDE 490

typedef _Float16 half8 __attribute__((ext_vector_type(8)));
typedef _Float16 half4 __attribute__((ext_vector_type(4)));
typedef float f32x4 __attribute__((ext_vector_type(4)));

union H8 { half8 h; uint4 u; };

// Fragment table layout (uint4 per lane, 64 lanes per fragment):
//   conv1 [0,18)   conv2 [18,54)   conv3 [54,126)
//   fc   [126,638): 32 ksteps x 16 mt      (K=1024)
//   t1   [638,798): 10 ksteps x 16 mt      (K=320)
//   t2   [798,926):  8 ksteps x 16 mt      (K=256)
//   head [926,942):  8 ksteps x 2 mt       (K=256; mt0=actor, mt1 row0=critic)
#define FC_BASE 126
#define T1_BASE 638
#define T2_BASE 798
#define HD_BASE 926
#define NFRAG   942

__global__ __launch_bounds__(256) void prep_weights(
    const float* __restrict__ w1, const float* __restrict__ w2,
    const float* __restrict__ w3,
    const float* __restrict__ fcw, const float* __restrict__ t1w,
    const float* __restrict__ t2w,
    const float* __restrict__ aw,  const float* __restrict__ cw,
    uint4* __restrict__ wfrag)
{
    int gid = blockIdx.x * 256 + threadIdx.x;
    if (gid >= NFRAG * 64) return;
    int fid = gid >> 6, lane = gid & 63;
    H8 v;
    if (fid < 126) {
        const float* W; int C, sh, kt, mt;
        if (fid < 18)      { int f = fid;      W = w1; C = 9;  sh = f >> 1; kt = 0;            mt = f & 1; }
        else if (fid < 54) { int f = fid - 18; W = w2; C = 32; sh = f >> 2; kt = 0;            mt = f & 3; }
        else               { int f = fid - 54; W = w3; C = 64; sh = f >> 3; kt = (f >> 2) & 1; mt = f & 3; }
        int o  = mt * 16 + (lane & 15);
        int c0 = kt * 32 + ((lane >> 4) << 3);
        #pragma unroll
        for (int i = 0; i < 8; ++i) {
            int c = c0 + i;
            v.h[i] = (c < C) ? (_Float16)W[(o * C + c) * 9 + sh] : (_Float16)0.f;
        }
    } else {
        int o16 = lane & 15, k0 = (lane >> 4) << 3;
        if (fid < HD_BASE) {
            const float* W; int K, f;
            if (fid < T1_BASE)      { f = fid - FC_BASE; W = fcw; K = 1024; }
            else if (fid < T2_BASE) { f = fid - T1_BASE; W = t1w; K = 320;  }
            else                    { f = fid - T2_BASE; W = t2w; K = 256;  }
            int ks = f >> 4, mtg = f & 15;
            int o = mtg * 16 + o16;
            int kb = ks * 32 + k0;
            #pragma unroll
            for (int i = 0; i < 8; ++i)
                v.h[i] = (_Float16)W[(size_t)o * K + kb + i];
        } else {
            int f = fid - HD_BASE;
            int ks = f >> 1, mtg = f & 1;
            int kb = ks * 32 + k0;
            #pragma unroll
            for (int i = 0; i < 8; ++i) {
                float x;
                if (mtg == 0)      x = aw[o16 * 256 + kb + i];
                else if (o16 == 0) x = cw[kb + i];
                else               x = 0.f;
                v.h[i] = (_Float16)x;
            }
        }
    }
    wfrag[gid] = v.u;
}

// ---------------------------------------------------------------------------
// conv_kernel (r13 best): round-5 geometry (18x18x128 Abuf, zero halo,
// 16B-chunk XOR swizzle), dx-major shift loop with 6-row register reuse:
// per (dx,kt) the 3 dy x 4 rows touch only rows wv*4..wv*4+5 -> load bf[6]
// ONCE, MFMA uses bf[row+dyi]. Halves ds_read_b128 count (144 -> 72 /wave).
// ---------------------------------------------------------------------------
template<int KT, int MT, int FRAG_BASE>
__device__ __forceinline__ void conv_layer(
    unsigned char* Abuf, const uint4* __restrict__ wfrag,
    const float* __restrict__ bias, int lane, int wv)
{
    const int x = lane & 15;
    const int q = lane >> 4;
    f32x4 acc[4][MT];
    #pragma unroll
    for (int mt = 0; mt < MT; ++mt) {
        f32x4 bv = *(const f32x4*)(bias + mt * 16 + q * 4);
        #pragma unroll
        for (int row = 0; row < 4; ++row) acc[row][mt] = bv;
    }
    #pragma unroll
    for (int dxi = 0; dxi < 3; ++dxi) {
        const int xs = x + dxi;                        // == x + dx + 1, 0..17
        #pragma unroll
        for (int kt = 0; kt < KT; ++kt) {
            const int chunk = ((kt * 4 + q) ^ (xs & 7)) << 4;
            // 6 distinct LDS rows cover all (row,dy) combos for this (dx,kt)
            H8 bf[6];
            #pragma unroll
            for (int j = 0; j < 6; ++j)
                bf[j].h = *(const half8*)(Abuf + (wv * 4 + j) * 2304 + xs * 128 + chunk);
            #pragma unroll
            for (int dyi = 0; dyi < 3; ++dyi) {
                const int sh = dyi * 3 + dxi;
                H8 wf[MT];
                #pragma unroll
                for (int mt = 0; mt < MT; ++mt)
                    wf[mt].u = wfrag[(FRAG_BASE + (sh * KT + kt) * MT + mt) * 64 + lane];
                #pragma unroll
                for (int row = 0; row < 4; ++row) {
                    // original ys = wv*4 + row + dy + 1 = wv*4 + (row + dyi)
                    #pragma unroll
                    for (int mt = 0; mt < MT; ++mt)
                        acc[row][mt] = __builtin_amdgcn_mfma_f32_16x16x32_f16(
                            wf[mt].h, bf[row + dyi].h, acc[row][mt], 0, 0, 0);
                }
            }
        }
    }
    __syncthreads();
    const int xs1 = x + 1;
    #pragma unroll
    for (int row = 0; row < 4; ++row) {
        const int ys = wv * 4 + row + 1;
        #pragma unroll
        for (int mt = 0; mt < MT; ++mt) {
            half4 hv;
            #pragma unroll
            for (int r = 0; r < 4; ++r) hv[r] = (_Float16)fmaxf(acc[row][mt][r], 0.f);
            const int ob = mt * 32 + q * 8;
            const int addr = ys * 2304 + xs1 * 128 + ((((ob >> 4) ^ (xs1 & 7))) << 4) + (ob & 15);
            *(half4*)(Abuf + addr) = hv;
        }
    }
    __syncthreads();
}

__global__ __launch_bounds__(256, 2) void conv_kernel(
    const float* __restrict__ obs,
    const uint4* __restrict__ wfrag,
    const float* __restrict__ b1, const float* __restrict__ b2,
    const float* __restrict__ b3,
    _Float16* __restrict__ pooled)
{
    __shared__ alignas(16) unsigned char Abuf[18 * 18 * 128];
    __shared__ float G[8][256];

    const int tid = threadIdx.x;
    const int b = blockIdx.x;
    const float* ob = obs + (size_t)b * OBS_STRIDE;

    {
        uint4 z = {0, 0, 0, 0};
        uint4* A4 = (uint4*)Abuf;
        for (int i = tid; i < 2592; i += 256) A4[i] = z;
        float4 zf = {0.f, 0.f, 0.f, 0.f};
        float4* G4 = (float4*)G;
        for (int i = tid; i < 512; i += 256) G4[i] = zf;
    }
    __syncthreads();

    if (tid < 20) {
        const float* up = ob + 256 + tid * 10;
        float team = up[1], rf = up[2], cf = up[3];
        float hp = up[4], mv = up[5], ac = up[6];
        if (hp > 0.f) {
            int r = (int)(rf * 15.f), c = (int)(cf * 15.f);
            int flat = r * 16 + c;
            if (team < 0.5f) {
                atomicAdd(&G[0][flat], 1.f);
                atomicAdd(&G[2][flat], hp);
                atomicAdd(&G[4][flat], mv);
                atomicAdd(&G[5][flat], ac);
            } else {
                atomicAdd(&G[1][flat], 1.f);
                atomicAdd(&G[3][flat], hp);
                atomicAdd(&G[6][flat], mv);
                atomicAdd(&G[7][flat], ac);
            }
        }
    }
    __syncthreads();

    {
        int p = tid & 255, xsg = (p & 15) + 1, ysg = (p >> 4) + 1;
        H8 v;
        v.h[0] = (_Float16)ob[p];
        #pragma unroll
        for (int c = 1; c < 8; ++c) v.h[c] = (_Float16)G[c - 1][p];
        *(uint4*)(Abuf + ysg * 2304 + xsg * 128 + ((xsg & 7) << 4)) = v.u;
        *(_Float16*)(Abuf + ysg * 2304 + xsg * 128 + ((1 ^ (xsg & 7)) << 4)) = (_Float16)G[7][p];
    }
    __syncthreads();

    const int lane = tid & 63, wv = tid >> 6;
    conv_layer<1, 2, 0 >(Abuf, wfrag, b1, lane, wv);   // 9(pad->32) -> 32
    conv_layer<1, 4, 18>(Abuf, wfrag, b2, lane, wv);   // 32 -> 64
    conv_layer<2, 4, 54>(Abuf, wfrag, b3, lane, wv);   // 64 -> 64

    {
        int qq = tid & 15, cg = tid >> 4;
        int ph = qq >> 2, pw = qq & 3;
        int ch0 = cg * 4;
        float s[4] = {0.f, 0.f, 0.f, 0.f};
        int ob2 = ch0 * 2;
        #pragma unroll
        for (int dy = 0; dy < 4; ++dy) {
            int ys = ph * 4 + dy + 1;
            #pragma unroll
            for (int dx = 0; dx < 4; ++dx) {
                int xs = pw * 4 + dx + 1;
                int addr = ys * 2304 + xs * 128 + ((((ob2 >> 4) ^ (xs & 7))) << 4) + (ob2 & 15);
                half4 hv = *(const half4*)(Abuf + addr);
                #pragma unroll
                for (int cc = 0; cc < 4; ++cc) s[cc] += (float)hv[cc];
            }
        }
        _Float16* pb = pooled + (size_t)b * 1024;
        #pragma unroll
        for (int cc = 0; cc < 4; ++cc)
            pb[(ch0 + cc) * 16 + qq] = (_Float16)(s[cc] * 0.0625f);
    }
}

// ---------------------------------------------------------------------------
// tail_kernel (MFMA): UNCHANGED (passed, ~30-50us).
// ---------------------------------------------------------------------------
__global__ __launch_bounds__(256) void tail_kernel(
    const float* __restrict__ obs,
    const _Float16* __restrict__ pooled,
    const uint4* __restrict__ wfrag,
    const float* __restrict__ fcb,
    const float* __restrict__ u1w, const float* __restrict__ u1b,
    const float* __restrict__ u2w, const float* __restrict__ u2b,
    const float* __restrict__ t1b, const float* __restrict__ t2b,
    const float* __restrict__ ab,  const float* __restrict__ cb,
    float* __restrict__ out, int NB)
{
    __shared__ alignas(16) _Float16 tcT[32][344];   // 22016 B
    __shared__ alignas(16) _Float16 uh[32][72];     //  4608 B

    const int tid  = threadIdx.x;
    const int lane = tid & 63, w = tid >> 6;
    const int nl   = lane & 15, q = lane >> 4;
    const int r0   = blockIdx.x * 32;

    // ---- unit MLP u1 (scalar): 32 rows x 8 threads each ----
    {
        const int r = tid >> 3, t8 = tid & 7;
        const float* up = obs + (size_t)(r0 + r) * OBS_STRIDE + 458;
        float xin[32];
        #pragma unroll
        for (int k2 = 0; k2 < 16; ++k2) {
            float2 v = *(const float2*)(up + k2 * 2);
            xin[k2 * 2] = v.x; xin[k2 * 2 + 1] = v.y;
        }
        #pragma unroll
        for (int oo = 0; oo < 8; ++oo) {
            int o = t8 * 8 + oo;
            float a = u1b[o];
            const float* wr = u1w + o * 32;
            #pragma unroll
            for (int k = 0; k < 32; ++k) a = fmaf(xin[k], wr[k], a);
            uh[r][o] = (_Float16)fmaxf(a, 0.f);
        }
    }
    __syncthreads();

    // ---- u2 -> tcT[:, 256..319] ----
    {
        const int r = tid >> 3, t8 = tid & 7;
        float xin[64];
        #pragma unroll
        for (int k8 = 0; k8 < 8; ++k8) {
            half8 v = *(const half8*)&uh[r][k8 * 8];
            #pragma unroll
            for (int j = 0; j < 8; ++j) xin[k8 * 8 + j] = (float)v[j];
        }
        #pragma unroll
        for (int oo = 0; oo < 8; ++oo) {
            int o = t8 * 8 + oo;
            float a = u2b[o];
            const float* wr = u2w + o * 64;
            #pragma unroll
            for (int k = 0; k < 64; ++k) a = fmaf(xin[k], wr[k], a);
            tcT[r][256 + o] = (_Float16)fmaxf(a, 0.f);
        }
    }

    // ---- fc: K=1024, 32 ksteps, B-frags direct from global pooled ----
    {
        f32x4 acc[4][2];
        #pragma unroll
        for (int mt = 0; mt < 4; ++mt) {
            f32x4 bv = *(const f32x4*)(fcb + (w * 4 + mt) * 16 + q * 4);
            acc[mt][0] = bv; acc[mt][1] = bv;
        }
        for (int ks = 0; ks < 32; ++ks) {
            H8 bf[2];
            #pragma unroll
            for (int g = 0; g < 2; ++g)
                bf[g].u = *(const uint4*)(pooled + (size_t)(r0 + g * 16 + nl) * 1024 + ks * 32 + q * 8);
            #pragma unroll
            for (int mt = 0; mt < 4; ++mt) {
                H8 af; af.u = wfrag[(size_t)(FC_BASE + ks * 16 + w * 4 + mt) * 64 + lane];
                #pragma unroll
                for (int g = 0; g < 2; ++g)
                    acc[mt][g] = __builtin_amdgcn_mfma_f32_16x16x32_f16(af.h, bf[g].h, acc[mt][g], 0, 0, 0);
            }
        }
        #pragma unroll
        for (int mt = 0; mt < 4; ++mt)
            #pragma unroll
            for (int g = 0; g < 2; ++g) {
                half4 hv;
                #pragma unroll
                for (int r = 0; r < 4; ++r) hv[r] = (_Float16)fmaxf(acc[mt][g][r], 0.f);
                *(half4*)&tcT[g * 16 + nl][(w * 4 + mt) * 16 + q * 4] = hv;
            }
    }
    __syncthreads();

    // ---- t1: K=320, 10 ksteps, B from tcT; in-place overwrite ----
    {
        f32x4 acc[4][2];
        #pragma unroll
        for (int mt = 0; mt < 4; ++mt) {
            f32x4 bv = *(const f32x4*)(t1b + (w * 4 + mt) * 16 + q * 4);
            acc[mt][0] = bv; acc[mt][1] = bv;
        }
        for (int ks = 0; ks < 10; ++ks) {
            H8 bf[2];
            #pragma unroll
            for (int g = 0; g < 2; ++g)
                bf[g].h = *(const half8*)&tcT[g * 16 + nl][ks * 32 + q * 8];
            #pragma unroll
            for (int mt = 0; mt < 4; ++mt) {
                H8 af; af.u = wfrag[(size_t)(T1_BASE + ks * 16 + w * 4 + mt) * 64 + lane];
                #pragma unroll
                for (int g = 0; g < 2; ++g)
                    acc[mt][g] = __builtin_amdgcn_mfma_f32_16x16x32_f16(af.h, bf[g].h, acc[mt][g], 0, 0, 0);
            }
        }
        __syncthreads();
        #pragma unroll
        for (int mt = 0; mt < 4; ++mt)
            #pragma unroll
            for (int g = 0; g < 2; ++g) {
                half4 hv;
                #pragma unroll
                for (int r = 0; r < 4; ++r) hv[r] = (_Float16)fmaxf(acc[mt][g][r], 0.f);
                *(half4*)&tcT[g * 16 + nl][(w * 4 + mt) * 16 + q * 4] = hv;
            }
    }
    __syncthreads();

    // ---- t2: K=256, 8 ksteps ----
    {
        f32x4 acc[4][2];
        #pragma unroll
        for (int mt = 0; mt < 4; ++mt) {
            f32x4 bv = *(const f32x4*)(t2b + (w * 4 + mt) * 16 + q * 4);
            acc[mt][0] = bv; acc[mt][1] = bv;
        }
        for (int ks = 0; ks < 8; ++ks) {
            H8 bf[2];
            #pragma unroll
            for (int g = 0; g < 2; ++g)
                bf[g].h = *(const half8*)&tcT[g * 16 + nl][ks * 32 + q * 8];
            #pragma unroll
            for (int mt = 0; mt < 4; ++mt) {
                H8 af; af.u = wfrag[(size_t)(T2_BASE + ks * 16 + w * 4 + mt) * 64 + lane];
                #pragma unroll
                for (int g = 0; g < 2; ++g)
                    acc[mt][g] = __builtin_amdgcn_mfma_f32_16x16x32_f16(af.h, bf[g].h, acc[mt][g], 0, 0, 0);
            }
        }
        __syncthreads();
        #pragma unroll
        for (int mt = 0; mt < 4; ++mt)
            #pragma unroll
            for (int g = 0; g < 2; ++g) {
                half4 hv;
                #pragma unroll
                for (int r = 0; r < 4; ++r) hv[r] = (_Float16)fmaxf(acc[mt][g][r], 0.f);
                *(half4*)&tcT[g * 16 + nl][(w * 4 + mt) * 16 + q * 4] = hv;
            }
    }
    __syncthreads();

    // ---- heads: K=256, 8 ksteps; wave0 = actor, wave1 = critic ----
    if (w < 2) {
        f32x4 acc[2];
        if (w == 0) {
            f32x4 bv = *(const f32x4*)(ab + q * 4);
            acc[0] = bv; acc[1] = bv;
        } else {
            f32x4 bv = {0.f, 0.f, 0.f, 0.f};
            if (q == 0) bv[0] = cb[0];
            acc[0] = bv; acc[1] = bv;
        }
        for (int ks = 0; ks < 8; ++ks) {
            H8 af; af.u = wfrag[(size_t)(HD_BASE + ks * 2 + w) * 64 + lane];
            #pragma unroll
            for (int g = 0; g < 2; ++g) {
                half8 bf = *(const half8*)&tcT[g * 16 + nl][ks * 32 + q * 8];
                acc[g] = __builtin_amdgcn_mfma_f32_16x16x32_f16(af.h, bf, acc[g], 0, 0, 0);
            }
        }
        if (w == 0) {
            #pragma unroll
            for (int g = 0; g < 2; ++g) {
                float4 o4 = {acc[g][0], acc[g][1], acc[g][2], acc[g][3]};
                *(float4*)(out + (size_t)(r0 + g * 16 + nl) * 16 + q * 4) = o4;
            }
        } else if (q == 0) {
            #pragma unroll
            for (int g = 0; g < 2; ++g)
                out[(size_t)NB * 16 + r0 + g * 16 + nl] = acc[g][0];
        }
    }
}

extern "C" void kernel_launch(void* const* d_in, const int* in_sizes, int n_in,
                              void* d_out, int out_size, void* d_ws, size_t ws_size,
                              hipStream_t stream)
{
    const float* obs = (const float*)d_in[0];
    const float* w1  = (const float*)d_in[1];
    const float* b1  = (const float*)d_in[2];
    const float* w2  = (const float*)d_in[3];
    const float* b2  = (const float*)d_in[4];
    const float* w3  = (const float*)d_in[5];
    const float* b3  = (const float*)d_in[6];
    const float* fcw = (const float*)d_in[7];
    const float* fcb = (const float*)d_in[8];
    const float* u1w = (const float*)d_in[9];
    const float* u1b = (const float*)d_in[10];
    const float* u2w = (const float*)d_in[11];
    const float* u2b = (const float*)d_in[12];
    const float* t1w = (const float*)d_in[13];
    const float* t1b = (const float*)d_in[14];
    const float* t2w = (const float*)d_in[15];
    const float* t2b = (const float*)d_in[16];
    const float* aw  = (const float*)d_in[17];
    const float* ab  = (const float*)d_in[18];
    const float* cw  = (const float*)d_in[19];
    const float* cb  = (const float*)d_in[20];

    const int NB = in_sizes[0] / OBS_STRIDE;                       // 16384
    _Float16* pooled = (_Float16*)d_ws;                            // 32 MB
    uint4* wfrag = (uint4*)((char*)d_ws + (size_t)NB * 1024 * 2);  // 942 KB

    prep_weights<<<(NFRAG * 64 + 255) / 256, 256, 0, stream>>>(
        w1, w2, w3, fcw, t1w, t2w, aw, cw, wfrag);
    conv_kernel<<<NB, 256, 0, stream>>>(obs, (const uint4*)wfrag, b1, b2, b3, pooled);
    tail_kernel<<<NB / 32, 256, 0, stream>>>(obs, pooled, (const uint4*)wfrag,
                                             fcb, u1w, u1b, u2w, u2b,
                                             t1b, t2b, ab, cb,
                                             (float*)d_out, NB);
}